// Round 3
// baseline (391.883 us; speedup 1.0000x reference)
//
#include <hip/hip_runtime.h>
#include <hip/hip_bf16.h>

#define HD 256
#define NN 32768
#define NE 262144
#define NB 128
#define NM 512

typedef short bf16x8 __attribute__((ext_vector_type(8)));
typedef float f32x4 __attribute__((ext_vector_type(4)));
typedef unsigned short u16;
typedef unsigned short u16x8 __attribute__((ext_vector_type(8)));
typedef unsigned short u16x4 __attribute__((ext_vector_type(4)));

__device__ __forceinline__ float b2f(u16 u) {
    unsigned int i = ((unsigned int)u) << 16;
    float f; __builtin_memcpy(&f, &i, 4); return f;
}
__device__ __forceinline__ u16 f2b(float f) {
    unsigned int i; __builtin_memcpy(&i, &f, 4);
    return (u16)((i + 0x7FFFu + ((i >> 16) & 1u)) >> 16);
}

// ---------------- CSR build ----------------
__global__ __launch_bounds__(256) void k_hist(const int* __restrict__ dst, int* __restrict__ deg) {
    int e = blockIdx.x * 256 + threadIdx.x;
    if (e < NE) atomicAdd(&deg[dst[e]], 1);
}

__global__ __launch_bounds__(1024) void k_scan(const int* __restrict__ deg,
                                               int* __restrict__ offs, int* __restrict__ cur) {
    __shared__ int sums[1024];
    int t = threadIdx.x;
    int base = t * 32;
    int loc[32];
    int s = 0;
#pragma unroll
    for (int i = 0; i < 32; i++) { loc[i] = s; s += deg[base + i]; }
    sums[t] = s;
    __syncthreads();
    for (int o = 1; o < 1024; o <<= 1) {
        int v = 0;
        if (t >= o) v = sums[t - o];
        __syncthreads();
        if (t >= o) sums[t] += v;
        __syncthreads();
    }
    int pre = sums[t] - s;
#pragma unroll
    for (int i = 0; i < 32; i++) { int v = pre + loc[i]; offs[base + i] = v; cur[base + i] = v; }
    if (t == 1023) offs[NN] = sums[1023];
}

__global__ __launch_bounds__(256) void k_fill(const int* __restrict__ src, const int* __restrict__ dst,
                                              int* __restrict__ cur, int* __restrict__ csr) {
    int e = blockIdx.x * 256 + threadIdx.x;
    if (e < NE) {
        int p = atomicAdd(&cur[dst[e]], 1);
        csr[p] = src[e];
    }
}

// deterministic neighbor order regardless of atomic fill order
__global__ __launch_bounds__(256) void k_sortcsr(const int* __restrict__ offs, int* __restrict__ csr) {
    int n = blockIdx.x * 256 + threadIdx.x;
    if (n >= NN) return;
    int o0 = offs[n], o1 = offs[n + 1];
    for (int i = o0 + 1; i < o1; i++) {
        int v = csr[i];
        int j = i - 1;
        while (j >= o0 && csr[j] > v) { csr[j + 1] = csr[j]; j--; }
        csr[j + 1] = v;
    }
}

// ---------------- weight transpose + f32->bf16 convert ----------------
__global__ __launch_bounds__(256) void k_transpose(const float* __restrict__ W, u16* __restrict__ Wt,
                                                   int K, int N) {
    int idx = blockIdx.x * 256 + threadIdx.x;
    if (idx < K * N) {
        int k = idx / N, n = idx - k * N;
        Wt[(size_t)n * K + k] = f2b(W[idx]);
    }
}

// ---------------- input projection ----------------
__global__ __launch_bounds__(256) void k_inproj(const float* __restrict__ x, const int* __restrict__ player,
                                                const float* __restrict__ Win, const float* __restrict__ bin,
                                                u16* __restrict__ h0) {
    const int j = threadIdx.x;
    const int node0 = blockIdx.x * 128;
    const int g = node0 >> 8;
    __shared__ float xs[128 * 32];
    for (int i = j; i < 128 * 32; i += 256) xs[i] = x[(size_t)node0 * 32 + i];
    float w[32];
#pragma unroll
    for (int k = 0; k < 32; k++) w[k] = Win[k * HD + j];
    const int pl = player[g];
    const float cadd = Win[(32 + pl) * HD + j] + bin[j];
    __syncthreads();
#pragma unroll 4
    for (int i = 0; i < 128; i++) {
        float a = cadd;
#pragma unroll
        for (int k = 0; k < 32; k++) a += xs[i * 32 + k] * w[k];
        h0[(size_t)(node0 + i) * HD + j] = f2b(a);
    }
}

// ---------------- fused GIN layer: CSR-agg (regs) + GEMM + bias + LN (+res) + ReLU ----------------
// One wave per 16 node rows. No LDS, no barriers. mfma(Wfrag, hfrag):
//   A-operand = Wt row n=fc*16+l15 (k slice), B-operand = aggregated h row m=m0+l15.
//   D: col=l15 -> node row m; row=lg*4+e -> output channel n=fc*16+lg*4+e.
__global__ __launch_bounds__(64) void k_gin_fused(const u16* __restrict__ h,
                                                  const int* __restrict__ offs, const int* __restrict__ csr,
                                                  const u16* __restrict__ Wt, const float* __restrict__ bias,
                                                  const float* __restrict__ lng, const float* __restrict__ lnb,
                                                  const u16* __restrict__ res, u16* __restrict__ hout) {
    const int lane = threadIdx.x;
    const int l15 = lane & 15, lg = lane >> 4;
    const int m = blockIdx.x * 16 + l15;

    // --- aggregate self + neighbors into f32 regs (lane holds cols ks*32+lg*8..+8) ---
    float vals[8][8];
    {
        const u16* hrow = h + (size_t)m * HD;
#pragma unroll
        for (int ks = 0; ks < 8; ks++) {
            u16x8 v = *(const u16x8*)(hrow + ks * 32 + lg * 8);
#pragma unroll
            for (int j = 0; j < 8; j++) vals[ks][j] = b2f(v[j]);
        }
    }
    const int o0 = offs[m], o1 = offs[m + 1];
    for (int e = o0; e < o1; e++) {
        const u16* srow = h + (size_t)csr[e] * HD;
#pragma unroll
        for (int ks = 0; ks < 8; ks++) {
            u16x8 v = *(const u16x8*)(srow + ks * 32 + lg * 8);
#pragma unroll
            for (int j = 0; j < 8; j++) vals[ks][j] += b2f(v[j]);
        }
    }
    // pack to bf16 A-fragments
    bf16x8 afr[8];
#pragma unroll
    for (int ks = 0; ks < 8; ks++)
#pragma unroll
        for (int j = 0; j < 8; j++) afr[ks][j] = (short)f2b(vals[ks][j]);

    // --- GEMM: 16 rows x 256 cols, W-frags straight from L2 ---
    f32x4 acc[16];
#pragma unroll
    for (int fc = 0; fc < 16; fc++) acc[fc] = (f32x4){0.f, 0.f, 0.f, 0.f};
#pragma unroll
    for (int ks = 0; ks < 8; ks++) {
#pragma unroll
        for (int fc = 0; fc < 16; fc++) {
            bf16x8 w = *(const bf16x8*)(Wt + (size_t)(fc * 16 + l15) * HD + ks * 32 + lg * 8);
            acc[fc] = __builtin_amdgcn_mfma_f32_16x16x32_bf16(w, afr[ks], acc[fc], 0, 0, 0);
        }
    }

    // --- bias + LayerNorm stats (row m lives in the 4 lanes sharing l15) ---
    float s = 0.f, q = 0.f;
#pragma unroll
    for (int fc = 0; fc < 16; fc++) {
        f32x4 b4 = *(const f32x4*)(bias + fc * 16 + lg * 4);
#pragma unroll
        for (int e = 0; e < 4; e++) {
            float z = acc[fc][e] + b4[e];
            acc[fc][e] = z;
            s += z; q += z * z;
        }
    }
    s += __shfl_xor(s, 16); s += __shfl_xor(s, 32);
    q += __shfl_xor(q, 16); q += __shfl_xor(q, 32);
    const float mean = s * (1.0f / HD);
    const float rinv = rsqrtf(q * (1.0f / HD) - mean * mean + 1e-5f);

    // --- apply LN (+residual) + ReLU, 8B stores ---
    const bool hasRes = (res != nullptr);
#pragma unroll
    for (int fc = 0; fc < 16; fc++) {
        f32x4 g4 = *(const f32x4*)(lng + fc * 16 + lg * 4);
        f32x4 e4 = *(const f32x4*)(lnb + fc * 16 + lg * 4);
        float y[4];
#pragma unroll
        for (int e = 0; e < 4; e++) y[e] = (acc[fc][e] - mean) * rinv * g4[e] + e4[e];
        if (hasRes) {
            u16x4 r = *(const u16x4*)(res + (size_t)m * HD + fc * 16 + lg * 4);
#pragma unroll
            for (int e = 0; e < 4; e++) y[e] += b2f(r[e]);
        }
        u16x4 o;
#pragma unroll
        for (int e = 0; e < 4; e++) o[e] = f2b(fmaxf(y[e], 0.f));
        *(u16x4*)(hout + (size_t)m * HD + fc * 16 + lg * 4) = o;
    }
}

// ---------------- global mean pool ----------------
__global__ __launch_bounds__(256) void k_pool(const u16* __restrict__ h, float* __restrict__ ge) {
    int g = blockIdx.x, j = threadIdx.x;
    const u16* p = h + (size_t)g * 256 * HD + j;
    float s = 0.f;
    for (int i = 0; i < 256; i++) s += b2f(p[(size_t)i * HD]);
    ge[g * HD + j] = s * (1.0f / 256.0f);
}

// ---------------- value head ----------------
__global__ __launch_bounds__(256) void k_value(const float* __restrict__ ge,
                                               const float* __restrict__ W1, const float* __restrict__ b1,
                                               const float* __restrict__ W2, const float* __restrict__ b2p,
                                               const float* __restrict__ g1, const float* __restrict__ be1,
                                               const float* __restrict__ m1, const float* __restrict__ v1,
                                               const float* __restrict__ g2, const float* __restrict__ be2,
                                               const float* __restrict__ m2, const float* __restrict__ v2,
                                               const float* __restrict__ Wv, const float* __restrict__ bv,
                                               float* __restrict__ out) {
    int g = blockIdx.x, j = threadIdx.x;
    __shared__ float buf[256];
    __shared__ float red[4];
    buf[j] = ge[g * HD + j];
    __syncthreads();
    float z = 0.f;
    for (int k = 0; k < HD; k++) z += buf[k] * W1[k * HD + j];
    z += b1[j];
    z = (z - m1[j]) * rsqrtf(v1[j] + 1e-5f) * g1[j] + be1[j];
    z = fmaxf(z, 0.f);
    __syncthreads();
    buf[j] = z;
    __syncthreads();
    float z2 = 0.f;
    for (int k = 0; k < HD; k++) z2 += buf[k] * W2[k * HD + j];
    z2 += b2p[j];
    z2 = (z2 - m2[j]) * rsqrtf(v2[j] + 1e-5f) * g2[j] + be2[j];
    z2 = fmaxf(z2, 0.f);
    float pv = z2 * Wv[j];
#pragma unroll
    for (int m = 1; m < 64; m <<= 1) pv += __shfl_xor(pv, m, 64);
    if ((j & 63) == 0) red[j >> 6] = pv;
    __syncthreads();
    if (j == 0) out[g] = tanhf(red[0] + red[1] + red[2] + red[3] + bv[0]);
}

// ---------------- fused policy head: gathered GEMM + relu + dot(Wp2), wave-independent ----------------
// One wave per 32 moves (two 16-move groups sharing W-fragments).
__global__ __launch_bounds__(64) void k_policy_fused(const u16* __restrict__ h,
                                                     const u16* __restrict__ Wp1t, const float* __restrict__ bp1,
                                                     const float* __restrict__ wp2, const float* __restrict__ bp2,
                                                     const int* __restrict__ mov, float* __restrict__ out) {
    const int lane = threadIdx.x;
    const int l15 = lane & 15, lg = lane >> 4;
    const int m0 = blockIdx.x * 32;

    int mA = m0 + l15, mB = m0 + 16 + l15;
    int a0 = mov[(size_t)mA * 2], b0 = mov[(size_t)mA * 2 + 1];
    int a1 = mov[(size_t)mB * 2], b1 = mov[(size_t)mB * 2 + 1];
    const int vld0 = (a0 != -1) && (b0 != -1);
    const int vld1 = (a1 != -1) && (b1 != -1);
    const int s0 = a0 < 0 ? 0 : a0, t0 = b0 < 0 ? 0 : b0;
    const int s1 = a1 < 0 ? 0 : a1, t1 = b1 < 0 ? 0 : b1;

    f32x4 acc0[16], acc1[16];
#pragma unroll
    for (int fc = 0; fc < 16; fc++) { acc0[fc] = (f32x4){0.f,0.f,0.f,0.f}; acc1[fc] = (f32x4){0.f,0.f,0.f,0.f}; }

#pragma unroll 4
    for (int ks = 0; ks < 16; ks++) {
        const int n0 = (ks < 8) ? s0 : t0;
        const int n1 = (ks < 8) ? s1 : t1;
        bf16x8 fa0 = *(const bf16x8*)(h + (size_t)n0 * HD + (ks & 7) * 32 + lg * 8);
        bf16x8 fa1 = *(const bf16x8*)(h + (size_t)n1 * HD + (ks & 7) * 32 + lg * 8);
#pragma unroll
        for (int fc = 0; fc < 16; fc++) {
            bf16x8 w = *(const bf16x8*)(Wp1t + (size_t)(fc * 16 + l15) * 512 + ks * 32 + lg * 8);
            acc0[fc] = __builtin_amdgcn_mfma_f32_16x16x32_bf16(w, fa0, acc0[fc], 0, 0, 0);
            acc1[fc] = __builtin_amdgcn_mfma_f32_16x16x32_bf16(w, fa1, acc1[fc], 0, 0, 0);
        }
    }

    float p0 = 0.f, p1 = 0.f;
#pragma unroll
    for (int fc = 0; fc < 16; fc++) {
        f32x4 b4 = *(const f32x4*)(bp1 + fc * 16 + lg * 4);
        f32x4 w4 = *(const f32x4*)(wp2 + fc * 16 + lg * 4);
#pragma unroll
        for (int e = 0; e < 4; e++) {
            p0 += fmaxf(acc0[fc][e] + b4[e], 0.f) * w4[e];
            p1 += fmaxf(acc1[fc][e] + b4[e], 0.f) * w4[e];
        }
    }
    p0 += __shfl_xor(p0, 16); p0 += __shfl_xor(p0, 32);
    p1 += __shfl_xor(p1, 16); p1 += __shfl_xor(p1, 32);
    if (lg == 0) {
        float bb = bp2[0];
        out[m0 + l15]      = vld0 ? p0 + bb : -1e9f;
        out[m0 + 16 + l15] = vld1 ? p1 + bb : -1e9f;
    }
}

extern "C" void kernel_launch(void* const* d_in, const int* in_sizes, int n_in,
                              void* d_out, int out_size, void* d_ws, size_t ws_size,
                              hipStream_t stream) {
    const float* x    = (const float*)d_in[0];
    const int* eidx   = (const int*)d_in[1];
    const int* mov    = (const int*)d_in[2];
    const int* player = (const int*)d_in[3];
    const float* Win  = (const float*)d_in[5];
    const float* b_in = (const float*)d_in[6];
    const float* Wg1 = (const float*)d_in[7],  *bg1 = (const float*)d_in[8];
    const float* Wg2 = (const float*)d_in[9],  *bg2 = (const float*)d_in[10];
    const float* Wg3 = (const float*)d_in[11], *bg3 = (const float*)d_in[12];
    const float* ln1g = (const float*)d_in[13], *ln1b = (const float*)d_in[14];
    const float* ln2g = (const float*)d_in[15], *ln2b = (const float*)d_in[16];
    const float* ln3g = (const float*)d_in[17], *ln3b = (const float*)d_in[18];
    const float* Wfc1 = (const float*)d_in[19], *bfc1 = (const float*)d_in[20];
    const float* Wfc2 = (const float*)d_in[21], *bfc2 = (const float*)d_in[22];
    const float* bn1g = (const float*)d_in[23], *bn1b = (const float*)d_in[24];
    const float* bn1m = (const float*)d_in[25], *bn1v = (const float*)d_in[26];
    const float* bn2g = (const float*)d_in[27], *bn2b = (const float*)d_in[28];
    const float* bn2m = (const float*)d_in[29], *bn2v = (const float*)d_in[30];
    const float* Wp1 = (const float*)d_in[31], *bp1 = (const float*)d_in[32];
    const float* Wp2 = (const float*)d_in[33], *bp2 = (const float*)d_in[34];
    const float* Wv  = (const float*)d_in[35], *bv  = (const float*)d_in[36];

    char* ws = (char*)d_ws;
    size_t off = 0;
    auto alloc = [&](size_t bytes) {
        size_t p = off;
        off = (off + bytes + 255) & ~(size_t)255;
        return (void*)(ws + p);
    };
    u16* h0   = (u16*)alloc((size_t)NN * HD * 2);
    u16* hA   = (u16*)alloc((size_t)NN * HD * 2);
    u16* hB   = (u16*)alloc((size_t)NN * HD * 2);
    u16* Wt1  = (u16*)alloc((size_t)HD * HD * 2);
    u16* Wt2  = (u16*)alloc((size_t)HD * HD * 2);
    u16* Wt3  = (u16*)alloc((size_t)HD * HD * 2);
    u16* Wp1t = (u16*)alloc((size_t)512 * HD * 2);
    int* deg  = (int*)alloc((size_t)NN * 4);
    int* offs = (int*)alloc((size_t)(NN + 1) * 4);
    int* cur  = (int*)alloc((size_t)NN * 4);
    int* csr  = (int*)alloc((size_t)NE * 4);
    float* ge = (float*)alloc((size_t)NB * HD * 4);

    const int* esrc = eidx;
    const int* edst = eidx + NE;

    hipMemsetAsync(deg, 0, (size_t)NN * 4, stream);
    k_hist<<<NE / 256, 256, 0, stream>>>(edst, deg);
    k_scan<<<1, 1024, 0, stream>>>(deg, offs, cur);
    k_fill<<<NE / 256, 256, 0, stream>>>(esrc, edst, cur, csr);
    k_sortcsr<<<NN / 256, 256, 0, stream>>>(offs, csr);

    k_transpose<<<(HD * HD + 255) / 256, 256, 0, stream>>>(Wg1, Wt1, HD, HD);
    k_transpose<<<(HD * HD + 255) / 256, 256, 0, stream>>>(Wg2, Wt2, HD, HD);
    k_transpose<<<(HD * HD + 255) / 256, 256, 0, stream>>>(Wg3, Wt3, HD, HD);
    k_transpose<<<(512 * HD + 255) / 256, 256, 0, stream>>>(Wp1, Wp1t, 512, HD);

    k_inproj<<<NN / 128, 256, 0, stream>>>(x, player, Win, b_in, h0);

    k_gin_fused<<<NN / 16, 64, 0, stream>>>(h0, offs, csr, Wt1, bg1, ln1g, ln1b, nullptr, hA);
    k_gin_fused<<<NN / 16, 64, 0, stream>>>(hA, offs, csr, Wt2, bg2, ln2g, ln2b, nullptr, hB);
    k_gin_fused<<<NN / 16, 64, 0, stream>>>(hB, offs, csr, Wt3, bg3, ln3g, ln3b, h0, hA);

    k_pool<<<NB, 256, 0, stream>>>(hA, ge);
    k_value<<<NB, 256, 0, stream>>>(ge, Wfc1, bfc1, Wfc2, bfc2,
                                    bn1g, bn1b, bn1m, bn1v, bn2g, bn2b, bn2m, bn2v,
                                    Wv, bv, ((float*)d_out) + NB * NM);
    k_policy_fused<<<(NB * NM) / 32, 64, 0, stream>>>(hA, Wp1t, bp1, Wp2, bp2, mov, (float*)d_out);
}

// Round 4
// 312.222 us; speedup vs baseline: 1.2551x; 1.2551x over previous
//
#include <hip/hip_runtime.h>
#include <hip/hip_bf16.h>

#define HD 256
#define NN 32768
#define NE 262144
#define NB 128
#define NM 512

typedef short bf16x8 __attribute__((ext_vector_type(8)));
typedef float f32x4 __attribute__((ext_vector_type(4)));
typedef unsigned short u16;
typedef unsigned short u16x8 __attribute__((ext_vector_type(8)));
typedef unsigned short u16x4 __attribute__((ext_vector_type(4)));

__device__ __forceinline__ float b2f(u16 u) {
    unsigned int i = ((unsigned int)u) << 16;
    float f; __builtin_memcpy(&f, &i, 4); return f;
}
__device__ __forceinline__ u16 f2b(float f) {
    unsigned int i; __builtin_memcpy(&i, &f, 4);
    return (u16)((i + 0x7FFFu + ((i >> 16) & 1u)) >> 16);
}

// ---------------- CSR build ----------------
__global__ __launch_bounds__(256) void k_hist(const int* __restrict__ dst, int* __restrict__ deg) {
    int e = blockIdx.x * 256 + threadIdx.x;
    if (e < NE) atomicAdd(&deg[dst[e]], 1);
}

__global__ __launch_bounds__(1024) void k_scan(const int* __restrict__ deg,
                                               int* __restrict__ offs, int* __restrict__ cur) {
    __shared__ int sums[1024];
    int t = threadIdx.x;
    int base = t * 32;
    int loc[32];
    int s = 0;
#pragma unroll
    for (int i = 0; i < 32; i++) { loc[i] = s; s += deg[base + i]; }
    sums[t] = s;
    __syncthreads();
    for (int o = 1; o < 1024; o <<= 1) {
        int v = 0;
        if (t >= o) v = sums[t - o];
        __syncthreads();
        if (t >= o) sums[t] += v;
        __syncthreads();
    }
    int pre = sums[t] - s;
#pragma unroll
    for (int i = 0; i < 32; i++) { int v = pre + loc[i]; offs[base + i] = v; cur[base + i] = v; }
    if (t == 1023) offs[NN] = sums[1023];
}

__global__ __launch_bounds__(256) void k_fill(const int* __restrict__ src, const int* __restrict__ dst,
                                              int* __restrict__ cur, int* __restrict__ csr) {
    int e = blockIdx.x * 256 + threadIdx.x;
    if (e < NE) {
        int p = atomicAdd(&cur[dst[e]], 1);
        csr[p] = src[e];
    }
}

__global__ __launch_bounds__(256) void k_sortcsr(const int* __restrict__ offs, int* __restrict__ csr) {
    int n = blockIdx.x * 256 + threadIdx.x;
    if (n >= NN) return;
    int o0 = offs[n], o1 = offs[n + 1];
    for (int i = o0 + 1; i < o1; i++) {
        int v = csr[i];
        int j = i - 1;
        while (j >= o0 && csr[j] > v) { csr[j + 1] = csr[j]; j--; }
        csr[j + 1] = v;
    }
}

// ---------------- weight transpose + f32->bf16 convert ----------------
// Wt[n*K + k] = W[k*N + n]
__global__ __launch_bounds__(256) void k_transpose(const float* __restrict__ W, u16* __restrict__ Wt,
                                                   int K, int N) {
    int idx = blockIdx.x * 256 + threadIdx.x;
    if (idx < K * N) {
        int k = idx / N, n = idx - k * N;
        Wt[(size_t)n * K + k] = f2b(W[idx]);
    }
}

// ---------------- input projection ----------------
__global__ __launch_bounds__(256) void k_inproj(const float* __restrict__ x, const int* __restrict__ player,
                                                const float* __restrict__ Win, const float* __restrict__ bin,
                                                u16* __restrict__ h0) {
    const int j = threadIdx.x;
    const int node0 = blockIdx.x * 128;
    const int g = node0 >> 8;
    __shared__ float xs[128 * 32];
    for (int i = j; i < 128 * 32; i += 256) xs[i] = x[(size_t)node0 * 32 + i];
    float w[32];
#pragma unroll
    for (int k = 0; k < 32; k++) w[k] = Win[k * HD + j];
    const int pl = player[g];
    const float cadd = Win[(32 + pl) * HD + j] + bin[j];
    __syncthreads();
#pragma unroll 4
    for (int i = 0; i < 128; i++) {
        float a = cadd;
#pragma unroll
        for (int k = 0; k < 32; k++) a += xs[i * 32 + k] * w[k];
        h0[(size_t)(node0 + i) * HD + j] = f2b(a);
    }
}

// ---------------- fused GIN layer: W in LDS (swizzled), reg agg, 1 barrier, MFMA ----------------
// 512 threads / 8 waves; block = 128 rows; wave w: rows bid*128 + w*16 + l15.
// mfma(Wfrag, hfrag): D col=l15 -> node row m; D row=lg*4+e -> channel fc*16+lg*4+e.
__global__ __launch_bounds__(512) void k_gin(const u16* __restrict__ h,
                                             const int* __restrict__ offs, const int* __restrict__ csr,
                                             const u16* __restrict__ Wt, const float* __restrict__ bias,
                                             const float* __restrict__ lng, const float* __restrict__ lnb,
                                             const u16* __restrict__ res, u16* __restrict__ hout) {
    const int tid = threadIdx.x;
    const int lane = tid & 63, wv = tid >> 6;
    const int l15 = lane & 15, lg = lane >> 4;
    const int m = blockIdx.x * 128 + wv * 16 + l15;

    __shared__ char Wl[256 * 512];   // 128 KiB, 16B-chunk XOR swizzle per row

    // --- stage W into LDS (each thread: half a row = 16 x 16B chunks) ---
    {
        const int n = tid >> 1, kh = tid & 1;
        const u16* srcw = Wt + n * HD + kh * 128;
        char* dstrow = Wl + n * 512;
        const int sw = (n & 7) << 4;
#pragma unroll
        for (int i = 0; i < 16; i++) {
            u16x8 v = *(const u16x8*)(srcw + i * 8);
            *(u16x8*)(dstrow + (((kh * 16 + i) * 16) ^ sw)) = v;
        }
    }

    // --- aggregate self + neighbors into f32 regs ---
    float vals[8][8];
    {
        const u16* hrow = h + (size_t)m * HD;
#pragma unroll
        for (int ks = 0; ks < 8; ks++) {
            u16x8 v = *(const u16x8*)(hrow + ks * 32 + lg * 8);
#pragma unroll
            for (int j = 0; j < 8; j++) vals[ks][j] = b2f(v[j]);
        }
    }
    const int o0 = offs[m], o1 = offs[m + 1];
    for (int e = o0; e < o1; e++) {
        const u16* srow = h + (size_t)csr[e] * HD;
#pragma unroll
        for (int ks = 0; ks < 8; ks++) {
            u16x8 v = *(const u16x8*)(srow + ks * 32 + lg * 8);
#pragma unroll
            for (int j = 0; j < 8; j++) vals[ks][j] += b2f(v[j]);
        }
    }
    bf16x8 afr[8];
#pragma unroll
    for (int ks = 0; ks < 8; ks++)
#pragma unroll
        for (int j = 0; j < 8; j++) afr[ks][j] = (short)f2b(vals[ks][j]);

    __syncthreads();

    // --- MFMA: 16 rows x 256 cols, W-frags from LDS (conflict-free swizzle) ---
    f32x4 acc[16];
#pragma unroll
    for (int fc = 0; fc < 16; fc++) acc[fc] = (f32x4){0.f, 0.f, 0.f, 0.f};
    const int swr = (l15 & 7) << 4;
#pragma unroll
    for (int ks = 0; ks < 8; ks++) {
#pragma unroll
        for (int fc = 0; fc < 16; fc++) {
            const char* wp = Wl + (fc * 16 + l15) * 512 + (((ks * 4 + lg) * 16) ^ swr);
            bf16x8 w = *(const bf16x8*)wp;
            acc[fc] = __builtin_amdgcn_mfma_f32_16x16x32_bf16(w, afr[ks], acc[fc], 0, 0, 0);
        }
    }

    // --- bias + LN stats ---
    float s = 0.f, q = 0.f;
#pragma unroll
    for (int fc = 0; fc < 16; fc++) {
        f32x4 b4 = *(const f32x4*)(bias + fc * 16 + lg * 4);
#pragma unroll
        for (int e = 0; e < 4; e++) {
            float z = acc[fc][e] + b4[e];
            acc[fc][e] = z;
            s += z; q += z * z;
        }
    }
    s += __shfl_xor(s, 16); s += __shfl_xor(s, 32);
    q += __shfl_xor(q, 16); q += __shfl_xor(q, 32);
    const float mean = s * (1.0f / HD);
    const float rinv = rsqrtf(q * (1.0f / HD) - mean * mean + 1e-5f);

    // --- LN (+res) + ReLU + store ---
    const bool hasRes = (res != nullptr);
#pragma unroll
    for (int fc = 0; fc < 16; fc++) {
        f32x4 g4 = *(const f32x4*)(lng + fc * 16 + lg * 4);
        f32x4 e4 = *(const f32x4*)(lnb + fc * 16 + lg * 4);
        float y[4];
#pragma unroll
        for (int e = 0; e < 4; e++) y[e] = (acc[fc][e] - mean) * rinv * g4[e] + e4[e];
        if (hasRes) {
            u16x4 r = *(const u16x4*)(res + (size_t)m * HD + fc * 16 + lg * 4);
#pragma unroll
            for (int e = 0; e < 4; e++) y[e] += b2f(r[e]);
        }
        u16x4 o;
#pragma unroll
        for (int e = 0; e < 4; e++) o[e] = f2b(fmaxf(y[e], 0.f));
        *(u16x4*)(hout + (size_t)m * HD + fc * 16 + lg * 4) = o;
    }
}

// ---------------- dense GEMM for policy precompute: hP = h @ Wt^T (+bias) ----------------
// grid 512: blocks 0..255 -> Wa -> hP1 (+bp1); 256..511 -> Wb -> hP2.
__global__ __launch_bounds__(512) void k_dense(const u16* __restrict__ h,
                                               const u16* __restrict__ Wta, const u16* __restrict__ Wtb,
                                               const float* __restrict__ bp1,
                                               u16* __restrict__ hP1, u16* __restrict__ hP2) {
    const int tid = threadIdx.x;
    const int lane = tid & 63, wv = tid >> 6;
    const int l15 = lane & 15, lg = lane >> 4;
    const int half = (blockIdx.x >= 256);
    const int m = (blockIdx.x & 255) * 128 + wv * 16 + l15;
    const u16* Wt = half ? Wtb : Wta;
    u16* outp = half ? hP2 : hP1;

    __shared__ char Wl[256 * 512];

    {
        const int n = tid >> 1, kh = tid & 1;
        const u16* srcw = Wt + n * HD + kh * 128;
        char* dstrow = Wl + n * 512;
        const int sw = (n & 7) << 4;
#pragma unroll
        for (int i = 0; i < 16; i++) {
            u16x8 v = *(const u16x8*)(srcw + i * 8);
            *(u16x8*)(dstrow + (((kh * 16 + i) * 16) ^ sw)) = v;
        }
    }

    bf16x8 afr[8];
    {
        const u16* hrow = h + (size_t)m * HD;
#pragma unroll
        for (int ks = 0; ks < 8; ks++) afr[ks] = *(const bf16x8*)(hrow + ks * 32 + lg * 8);
    }

    __syncthreads();

    f32x4 acc[16];
#pragma unroll
    for (int fc = 0; fc < 16; fc++) acc[fc] = (f32x4){0.f, 0.f, 0.f, 0.f};
    const int swr = (l15 & 7) << 4;
#pragma unroll
    for (int ks = 0; ks < 8; ks++) {
#pragma unroll
        for (int fc = 0; fc < 16; fc++) {
            const char* wp = Wl + (fc * 16 + l15) * 512 + (((ks * 4 + lg) * 16) ^ swr);
            bf16x8 w = *(const bf16x8*)wp;
            acc[fc] = __builtin_amdgcn_mfma_f32_16x16x32_bf16(w, afr[ks], acc[fc], 0, 0, 0);
        }
    }

#pragma unroll
    for (int fc = 0; fc < 16; fc++) {
        float b4[4] = {0.f, 0.f, 0.f, 0.f};
        if (!half) {
            f32x4 bb = *(const f32x4*)(bp1 + fc * 16 + lg * 4);
#pragma unroll
            for (int e = 0; e < 4; e++) b4[e] = bb[e];
        }
        u16x4 o;
#pragma unroll
        for (int e = 0; e < 4; e++) o[e] = f2b(acc[fc][e] + b4[e]);
        *(u16x4*)(outp + (size_t)m * HD + fc * 16 + lg * 4) = o;
    }
}

// ---------------- per-move: logit = relu(hP1[s] + hP2[t]) . Wp2 + bp2 ----------------
__global__ __launch_bounds__(64) void k_moves(const u16* __restrict__ hP1, const u16* __restrict__ hP2,
                                              const float* __restrict__ wp2, const float* __restrict__ bp2,
                                              const int* __restrict__ mov, float* __restrict__ out) {
    const int mi = blockIdx.x * 64 + threadIdx.x;
    int a = mov[(size_t)mi * 2], b = mov[(size_t)mi * 2 + 1];
    const bool vld = (a != -1) && (b != -1);
    const int s = a < 0 ? 0 : a, t = b < 0 ? 0 : b;
    const u16* r1 = hP1 + (size_t)s * HD;
    const u16* r2 = hP2 + (size_t)t * HD;
    float acc = 0.f;
#pragma unroll
    for (int c = 0; c < 32; c++) {
        u16x8 v1 = *(const u16x8*)(r1 + c * 8);
        u16x8 v2 = *(const u16x8*)(r2 + c * 8);
#pragma unroll
        for (int j = 0; j < 8; j++) {
            float z = b2f(v1[j]) + b2f(v2[j]);
            acc += fmaxf(z, 0.f) * wp2[c * 8 + j];
        }
    }
    out[mi] = vld ? acc + bp2[0] : -1e9f;
}

// ---------------- global mean pool ----------------
__global__ __launch_bounds__(256) void k_pool(const u16* __restrict__ h, float* __restrict__ ge) {
    int g = blockIdx.x, j = threadIdx.x;
    const u16* p = h + (size_t)g * 256 * HD + j;
    float s = 0.f;
    for (int i = 0; i < 256; i++) s += b2f(p[(size_t)i * HD]);
    ge[g * HD + j] = s * (1.0f / 256.0f);
}

// ---------------- value head ----------------
__global__ __launch_bounds__(256) void k_value(const float* __restrict__ ge,
                                               const float* __restrict__ W1, const float* __restrict__ b1,
                                               const float* __restrict__ W2, const float* __restrict__ b2p,
                                               const float* __restrict__ g1, const float* __restrict__ be1,
                                               const float* __restrict__ m1, const float* __restrict__ v1,
                                               const float* __restrict__ g2, const float* __restrict__ be2,
                                               const float* __restrict__ m2, const float* __restrict__ v2,
                                               const float* __restrict__ Wv, const float* __restrict__ bv,
                                               float* __restrict__ out) {
    int g = blockIdx.x, j = threadIdx.x;
    __shared__ float buf[256];
    __shared__ float red[4];
    buf[j] = ge[g * HD + j];
    __syncthreads();
    float z = 0.f;
    for (int k = 0; k < HD; k++) z += buf[k] * W1[k * HD + j];
    z += b1[j];
    z = (z - m1[j]) * rsqrtf(v1[j] + 1e-5f) * g1[j] + be1[j];
    z = fmaxf(z, 0.f);
    __syncthreads();
    buf[j] = z;
    __syncthreads();
    float z2 = 0.f;
    for (int k = 0; k < HD; k++) z2 += buf[k] * W2[k * HD + j];
    z2 += b2p[j];
    z2 = (z2 - m2[j]) * rsqrtf(v2[j] + 1e-5f) * g2[j] + be2[j];
    z2 = fmaxf(z2, 0.f);
    float pv = z2 * Wv[j];
#pragma unroll
    for (int m = 1; m < 64; m <<= 1) pv += __shfl_xor(pv, m, 64);
    if ((j & 63) == 0) red[j >> 6] = pv;
    __syncthreads();
    if (j == 0) out[g] = tanhf(red[0] + red[1] + red[2] + red[3] + bv[0]);
}

extern "C" void kernel_launch(void* const* d_in, const int* in_sizes, int n_in,
                              void* d_out, int out_size, void* d_ws, size_t ws_size,
                              hipStream_t stream) {
    const float* x    = (const float*)d_in[0];
    const int* eidx   = (const int*)d_in[1];
    const int* mov    = (const int*)d_in[2];
    const int* player = (const int*)d_in[3];
    const float* Win  = (const float*)d_in[5];
    const float* b_in = (const float*)d_in[6];
    const float* Wg1 = (const float*)d_in[7],  *bg1 = (const float*)d_in[8];
    const float* Wg2 = (const float*)d_in[9],  *bg2 = (const float*)d_in[10];
    const float* Wg3 = (const float*)d_in[11], *bg3 = (const float*)d_in[12];
    const float* ln1g = (const float*)d_in[13], *ln1b = (const float*)d_in[14];
    const float* ln2g = (const float*)d_in[15], *ln2b = (const float*)d_in[16];
    const float* ln3g = (const float*)d_in[17], *ln3b = (const float*)d_in[18];
    const float* Wfc1 = (const float*)d_in[19], *bfc1 = (const float*)d_in[20];
    const float* Wfc2 = (const float*)d_in[21], *bfc2 = (const float*)d_in[22];
    const float* bn1g = (const float*)d_in[23], *bn1b = (const float*)d_in[24];
    const float* bn1m = (const float*)d_in[25], *bn1v = (const float*)d_in[26];
    const float* bn2g = (const float*)d_in[27], *bn2b = (const float*)d_in[28];
    const float* bn2m = (const float*)d_in[29], *bn2v = (const float*)d_in[30];
    const float* Wp1 = (const float*)d_in[31], *bp1 = (const float*)d_in[32];
    const float* Wp2 = (const float*)d_in[33], *bp2 = (const float*)d_in[34];
    const float* Wv  = (const float*)d_in[35], *bv  = (const float*)d_in[36];

    char* ws = (char*)d_ws;
    size_t off = 0;
    auto alloc = [&](size_t bytes) {
        size_t p = off;
        off = (off + bytes + 255) & ~(size_t)255;
        return (void*)(ws + p);
    };
    u16* h0   = (u16*)alloc((size_t)NN * HD * 2);
    u16* hA   = (u16*)alloc((size_t)NN * HD * 2);
    u16* hB   = (u16*)alloc((size_t)NN * HD * 2);
    u16* Wt1  = (u16*)alloc((size_t)HD * HD * 2);
    u16* Wt2  = (u16*)alloc((size_t)HD * HD * 2);
    u16* Wt3  = (u16*)alloc((size_t)HD * HD * 2);
    u16* Wta  = (u16*)alloc((size_t)HD * HD * 2);
    u16* Wtb  = (u16*)alloc((size_t)HD * HD * 2);
    int* deg  = (int*)alloc((size_t)NN * 4);
    int* offs = (int*)alloc((size_t)(NN + 1) * 4);
    int* cur  = (int*)alloc((size_t)NN * 4);
    int* csr  = (int*)alloc((size_t)NE * 4);
    float* ge = (float*)alloc((size_t)NB * HD * 4);

    const int* esrc = eidx;
    const int* edst = eidx + NE;

    hipMemsetAsync(deg, 0, (size_t)NN * 4, stream);
    k_hist<<<NE / 256, 256, 0, stream>>>(edst, deg);
    k_scan<<<1, 1024, 0, stream>>>(deg, offs, cur);
    k_fill<<<NE / 256, 256, 0, stream>>>(esrc, edst, cur, csr);
    k_sortcsr<<<NN / 256, 256, 0, stream>>>(offs, csr);

    k_transpose<<<(HD * HD + 255) / 256, 256, 0, stream>>>(Wg1, Wt1, HD, HD);
    k_transpose<<<(HD * HD + 255) / 256, 256, 0, stream>>>(Wg2, Wt2, HD, HD);
    k_transpose<<<(HD * HD + 255) / 256, 256, 0, stream>>>(Wg3, Wt3, HD, HD);
    k_transpose<<<(HD * HD + 255) / 256, 256, 0, stream>>>(Wp1, Wta, HD, HD);
    k_transpose<<<(HD * HD + 255) / 256, 256, 0, stream>>>(Wp1 + HD * HD, Wtb, HD, HD);

    k_inproj<<<NN / 128, 256, 0, stream>>>(x, player, Win, b_in, h0);

    k_gin<<<NN / 128, 512, 0, stream>>>(h0, offs, csr, Wt1, bg1, ln1g, ln1b, nullptr, hA);
    k_gin<<<NN / 128, 512, 0, stream>>>(hA, offs, csr, Wt2, bg2, ln2g, ln2b, nullptr, hB);
    k_gin<<<NN / 128, 512, 0, stream>>>(hB, offs, csr, Wt3, bg3, ln3g, ln3b, h0, hA);

    // reuse hB as hP1, h0 as hP2 (both dead after layer 3)
    u16* hP1 = hB;
    u16* hP2 = h0;

    k_pool<<<NB, 256, 0, stream>>>(hA, ge);
    k_value<<<NB, 256, 0, stream>>>(ge, Wfc1, bfc1, Wfc2, bfc2,
                                    bn1g, bn1b, bn1m, bn1v, bn2g, bn2b, bn2m, bn2v,
                                    Wv, bv, ((float*)d_out) + NB * NM);

    k_dense<<<512, 512, 0, stream>>>(hA, Wta, Wtb, bp1, hP1, hP2);
    k_moves<<<(NB * NM) / 64, 64, 0, stream>>>(hP1, hP2, Wp2, bp2, mov, (float*)d_out);
}